// Round 3
// baseline (1760.321 us; speedup 1.0000x reference)
//
#include <hip/hip_runtime.h>
#include <hip/hip_bf16.h>
#include <math.h>

// Problem constants
#define N_E    4096      // number of codes
#define EDIM   256       // embedding dim (K)
#define SPAT   8192      // 8*32*32 spatial per (b,c)
#define NROWS  16384     // NB * SPAT flattened rows
#define ZELEMS 4194304   // 2*256*8*32*32
#define NCHUNK 4         // code-dim split for occupancy
#define CHUNKC 1024      // codes per chunk

// Output offsets (flat float32 in return order)
#define OFF_LOSS    0
#define OFF_ZQ      1
#define OFF_PERP    4194305
#define OFF_ONEHOT  4194306
#define OFF_IDX     71303170
#define OFF_ZOUT    71319554
#define OFF_EMA     75513858

// ---------------------------------------------------------------------------
// K0: se[c] = sum_k W[c][k]^2   (one wave per code)
// ---------------------------------------------------------------------------
__global__ __launch_bounds__(256) void se_kernel(const float* __restrict__ W,
                                                 float* __restrict__ se) {
    int wid  = (blockIdx.x * 256 + threadIdx.x) >> 6;   // wave id = code id
    int lane = threadIdx.x & 63;
    if (wid < N_E) {
        const float4 v = *(const float4*)(W + (size_t)wid * EDIM + lane * 4);
        float s = v.x * v.x + v.y * v.y + v.z * v.z + v.w * v.w;
        #pragma unroll
        for (int off = 32; off > 0; off >>= 1) s += __shfl_down(s, off);
        if (lane == 0) se[wid] = s;
    }
}

// ---------------------------------------------------------------------------
// K1: partial argmin. Grid (256 row-tiles, 4 code-chunks). Each block:
// 64 rows x 1024 codes, fp32 vector GEMM, BM=64 BN=128 BK=32, 512 thr, 4x4.
// LDS: GEMM tiles (24KB) aliased with reduction buffers (16KB) via union.
// __launch_bounds__(512, 4): VGPR cap 128 — R2's (512,8) capped VGPR at 32
// and caused spills + scalarized LDS reads (4.2e8 bank conflicts). ~60 VGPR
// allows 8 waves/EU anyway; LDS 25.5KB allows 6 blocks/CU; grid gives 4.
// ---------------------------------------------------------------------------
union SMem {
    struct { float As[32][64]; float Bs[32][128]; } mm;   // 24 KB
    struct { float bD[32][64]; int bI[32][64]; } red;     // 16 KB
};

__global__ __launch_bounds__(512, 4) void argmin_kernel(
        const float* __restrict__ z, const float* __restrict__ W,
        const float* __restrict__ se,
        float* __restrict__ bDw, int* __restrict__ bIw) {
    __shared__ SMem sh;
    __shared__ float szp[4][64];
    __shared__ float sz_s[64];

    const int tid   = threadIdx.x;
    const int r0    = blockIdx.x * 64;        // first row of tile
    const int chunk = blockIdx.y;             // code chunk
    const int bb    = r0 >> 13;               // batch index
    const int sp0   = r0 & (SPAT - 1);        // spatial base (multiple of 64)
    const float* zb = z + (size_t)bb * (EDIM * SPAT) + sp0;

    // row norms: 256 threads, 4 k-chunks of 64 each
    if (tid < 256) {
        int lr = tid & 63, kq = tid >> 6;
        float s = 0.f;
        const float* p = zb + lr + (size_t)(kq * 64) * SPAT;
        for (int k = 0; k < 64; ++k) {
            float v = p[(size_t)k * SPAT];
            s += v * v;
        }
        szp[kq][lr] = s;
    }
    __syncthreads();
    if (tid < 64)
        sz_s[tid] = ((szp[0][tid] + szp[1][tid]) + szp[2][tid]) + szp[3][tid];

    const int rg = tid >> 5;          // 0..15 -> rows rg*4..+3
    const int cg = tid & 31;          // 0..31 -> cols cg*4..+3 within chunk
    const int a_kk = tid >> 4;              // 0..31
    const int a_lr = (tid & 15) << 2;       // 0,4,..,60
    const int b_lc = tid & 127;             // 0..127
    const int b_kq = tid >> 7;              // 0..3

    float bestD[4];
    int   bestI[4];
    #pragma unroll
    for (int i = 0; i < 4; ++i) { bestD[i] = 3.4e38f; bestI[i] = 0; }

    const int cbeg = chunk * CHUNKC;
    for (int c0 = cbeg; c0 < cbeg + CHUNKC; c0 += 128) {
        float acc[4][4];
        #pragma unroll
        for (int i = 0; i < 4; ++i)
            #pragma unroll
            for (int j = 0; j < 4; ++j) acc[i][j] = 0.f;

        for (int k0 = 0; k0 < EDIM; k0 += 32) {
            __syncthreads();   // previous iter's LDS reads done
            const float4 av = *(const float4*)(zb + (size_t)(k0 + a_kk) * SPAT + a_lr);
            *(float4*)&sh.mm.As[a_kk][a_lr] = av;
            #pragma unroll
            for (int t = 0; t < 2; ++t) {
                int kk = b_kq * 8 + t * 4;
                const float4 bv = *(const float4*)(W + (size_t)(c0 + b_lc) * EDIM + k0 + kk);
                sh.mm.Bs[kk + 0][b_lc] = bv.x;
                sh.mm.Bs[kk + 1][b_lc] = bv.y;
                sh.mm.Bs[kk + 2][b_lc] = bv.z;
                sh.mm.Bs[kk + 3][b_lc] = bv.w;
            }
            __syncthreads();
            #pragma unroll
            for (int kk = 0; kk < 32; ++kk) {
                const float4 a = *(const float4*)&sh.mm.As[kk][rg << 2];
                const float4 b = *(const float4*)&sh.mm.Bs[kk][cg << 2];
                acc[0][0] += a.x * b.x; acc[0][1] += a.x * b.y;
                acc[0][2] += a.x * b.z; acc[0][3] += a.x * b.w;
                acc[1][0] += a.y * b.x; acc[1][1] += a.y * b.y;
                acc[1][2] += a.y * b.z; acc[1][3] += a.y * b.w;
                acc[2][0] += a.z * b.x; acc[2][1] += a.z * b.y;
                acc[2][2] += a.z * b.z; acc[2][3] += a.z * b.w;
                acc[3][0] += a.w * b.x; acc[3][1] += a.w * b.y;
                acc[3][2] += a.w * b.z; acc[3][3] += a.w * b.w;
            }
        }
        // distances + running argmin (codes ascend => first-min kept)
        #pragma unroll
        for (int i = 0; i < 4; ++i) {
            const float szr = sz_s[(rg << 2) + i];
            #pragma unroll
            for (int j = 0; j < 4; ++j) {
                const int code = c0 + (cg << 2) + j;
                const float d = (szr + se[code]) - 2.0f * acc[i][j];
                if (d < bestD[i]) { bestD[i] = d; bestI[i] = code; }
            }
        }
    }

    // cross-thread reduction per row (lexicographic on (d, idx))
    __syncthreads();   // As/Bs reads done before aliasing with red
    #pragma unroll
    for (int i = 0; i < 4; ++i) {
        sh.red.bD[cg][(rg << 2) + i] = bestD[i];
        sh.red.bI[cg][(rg << 2) + i] = bestI[i];
    }
    __syncthreads();
    if (tid < 64) {
        float d0 = sh.red.bD[0][tid];
        int   i0 = sh.red.bI[0][tid];
        #pragma unroll
        for (int c = 1; c < 32; ++c) {
            float d = sh.red.bD[c][tid];
            int   ii = sh.red.bI[c][tid];
            if (d < d0 || (d == d0 && ii < i0)) { d0 = d; i0 = ii; }
        }
        bDw[chunk * NROWS + r0 + tid] = d0;
        bIw[chunk * NROWS + r0 + tid] = i0;
    }
}

// ---------------------------------------------------------------------------
// K1b: combine partial argmins + write one-hot rows (zeros AND ones, fused,
// replaces the 256MB memset). One wave per row.
// ---------------------------------------------------------------------------
__global__ __launch_bounds__(256) void combine_kernel(
        const float* __restrict__ bDw, const int* __restrict__ bIw,
        int* __restrict__ idx_ws, int* __restrict__ counts,
        float* __restrict__ out_idx, float* __restrict__ out_onehot) {
    const int g    = blockIdx.x * 256 + threadIdx.x;
    const int row  = g >> 6;          // wave-per-row
    const int lane = g & 63;

    float d0 = bDw[row];
    int   i0 = bIw[row];
    #pragma unroll
    for (int c = 1; c < NCHUNK; ++c) {
        const float d  = bDw[c * NROWS + row];
        const int   ii = bIw[c * NROWS + row];
        if (d < d0 || (d == d0 && ii < i0)) { d0 = d; i0 = ii; }
    }
    if (lane == 0) {
        idx_ws[row]  = i0;
        out_idx[row] = (float)i0;
        atomicAdd(&counts[i0], 1);
    }
    float* dst = out_onehot + (size_t)row * N_E;
    #pragma unroll
    for (int w = 0; w < 16; ++w) {
        const int cb = w * 256 + lane * 4;
        float4 v;
        v.x = (cb + 0 == i0) ? 1.0f : 0.0f;
        v.y = (cb + 1 == i0) ? 1.0f : 0.0f;
        v.z = (cb + 2 == i0) ? 1.0f : 0.0f;
        v.w = (cb + 3 == i0) ? 1.0f : 0.0f;
        *(float4*)(dst + cb) = v;
    }
}

// ---------------------------------------------------------------------------
// K2: z_q_out, z_out, loss partial sums
// ---------------------------------------------------------------------------
__global__ __launch_bounds__(256) void outputs_kernel(
        const float* __restrict__ z, const float* __restrict__ W,
        const int* __restrict__ idx,
        float* __restrict__ zq_out, float* __restrict__ z_out,
        double* __restrict__ loss_acc) {
    const int t  = blockIdx.x * 256 + threadIdx.x;     // 0..ZELEMS-1
    const float zv = z[t];
    const int sp = t & (SPAT - 1);
    const int c  = (t >> 13) & 255;
    const int b  = t >> 21;
    const int n  = (b << 13) + sp;
    const int id = idx[n];
    const float e    = W[id * EDIM + c];
    const float diff = e - zv;        // z_q - zp
    zq_out[t] = zv + diff;            // straight-through value, exact rounding
    z_out[t]  = zv;

    double ds = (double)(diff * diff);
    #pragma unroll
    for (int off = 32; off > 0; off >>= 1) ds += __shfl_down(ds, off);
    __shared__ double bsum[4];
    const int lane = threadIdx.x & 63, w = threadIdx.x >> 6;
    if (lane == 0) bsum[w] = ds;
    __syncthreads();
    if (threadIdx.x == 0)
        atomicAdd(loss_acc, bsum[0] + bsum[1] + bsum[2] + bsum[3]);
}

// ---------------------------------------------------------------------------
// K3: EMA buffer update
// ---------------------------------------------------------------------------
__global__ __launch_bounds__(256) void ema_kernel(const float* __restrict__ W,
                                                  const float* __restrict__ ema,
                                                  float* __restrict__ out) {
    const int t = blockIdx.x * 256 + threadIdx.x;   // 0..1048575
    out[t] = 0.25f * ema[t] + 0.75f * W[t];
}

// ---------------------------------------------------------------------------
// K4: perplexity + loss finalize (single block)
// ---------------------------------------------------------------------------
__global__ __launch_bounds__(256) void final_kernel(
        const int* __restrict__ counts, const double* __restrict__ loss_acc,
        float* __restrict__ out_loss, float* __restrict__ out_perp) {
    __shared__ float ps[256];
    float s = 0.f;
    for (int c = threadIdx.x; c < N_E; c += 256) {
        const float p = (float)counts[c] * (1.0f / (float)NROWS);
        s += p * logf(p + 1e-10f);
    }
    ps[threadIdx.x] = s;
    __syncthreads();
    for (int off = 128; off > 0; off >>= 1) {
        if (threadIdx.x < off) ps[threadIdx.x] += ps[threadIdx.x + off];
        __syncthreads();
    }
    if (threadIdx.x == 0) {
        *out_perp = expf(-ps[0]);
        const float m = (float)(*loss_acc / (double)ZELEMS);
        *out_loss = m + 0.25f * m;
    }
}

// ---------------------------------------------------------------------------
extern "C" void kernel_launch(void* const* d_in, const int* in_sizes, int n_in,
                              void* d_out, int out_size, void* d_ws, size_t ws_size,
                              hipStream_t stream) {
    const float* z   = (const float*)d_in[0];
    const float* W   = (const float*)d_in[1];
    const float* ema = (const float*)d_in[2];
    float* out = (float*)d_out;

    float* out_loss   = out + OFF_LOSS;
    float* out_zq     = out + OFF_ZQ;
    float* out_perp   = out + OFF_PERP;
    float* out_onehot = out + OFF_ONEHOT;
    float* out_idx    = out + OFF_IDX;
    float* out_z      = out + OFF_ZOUT;
    float* out_ema    = out + OFF_EMA;

    // workspace layout
    char* ws = (char*)d_ws;
    double* loss_acc = (double*)ws;                        // 16 B
    int*    counts   = (int*)(ws + 16);                    // 16 KB
    int*    idxb     = (int*)(ws + 16 + 16384);            // 64 KB
    float*  se       = (float*)(ws + 16 + 16384 + 65536);  // 16 KB
    float*  bDw      = (float*)(ws + 16 + 16384 + 65536 + 16384);           // 256 KB
    int*    bIw      = (int*)  (ws + 16 + 16384 + 65536 + 16384 + 262144);  // 256 KB

    hipMemsetAsync(d_ws, 0, 16 + 16384, stream);   // loss + counts

    se_kernel<<<1024, 256, 0, stream>>>(W, se);
    argmin_kernel<<<dim3(NROWS / 64, NCHUNK), 512, 0, stream>>>(z, W, se, bDw, bIw);
    combine_kernel<<<NROWS * 64 / 256, 256, 0, stream>>>(bDw, bIw, idxb, counts,
                                                         out_idx, out_onehot);
    outputs_kernel<<<ZELEMS / 256, 256, 0, stream>>>(z, W, idxb, out_zq, out_z,
                                                     loss_acc);
    ema_kernel<<<(N_E * EDIM) / 256, 256, 0, stream>>>(W, ema, out_ema);
    final_kernel<<<1, 256, 0, stream>>>(counts, loss_acc, out_loss, out_perp);
}

// Round 4
// 994.687 us; speedup vs baseline: 1.7697x; 1.7697x over previous
//
#include <hip/hip_runtime.h>
#include <hip/hip_bf16.h>
#include <math.h>

// Problem constants
#define N_E    4096      // number of codes
#define EDIM   256       // embedding dim (K)
#define SPAT   8192      // 8*32*32 spatial per (b,c)
#define NROWS  16384     // NB * SPAT flattened rows
#define ZELEMS 4194304   // 2*256*8*32*32
#define NCHUNK 4         // code-dim split for occupancy
#define CHUNKC 1024      // codes per chunk

// Output offsets (flat float32 in return order)
#define OFF_LOSS    0
#define OFF_ZQ      1
#define OFF_PERP    4194305
#define OFF_ONEHOT  4194306
#define OFF_IDX     71303170
#define OFF_ZOUT    71319554
#define OFF_EMA     75513858

// ---------------------------------------------------------------------------
// K0: se[c] = sum_k W[c][k]^2   (one wave per code)
// ---------------------------------------------------------------------------
__global__ __launch_bounds__(256) void se_kernel(const float* __restrict__ W,
                                                 float* __restrict__ se) {
    int wid  = (blockIdx.x * 256 + threadIdx.x) >> 6;   // wave id = code id
    int lane = threadIdx.x & 63;
    if (wid < N_E) {
        const float4 v = *(const float4*)(W + (size_t)wid * EDIM + lane * 4);
        float s = v.x * v.x + v.y * v.y + v.z * v.z + v.w * v.w;
        #pragma unroll
        for (int off = 32; off > 0; off >>= 1) s += __shfl_down(s, off);
        if (lane == 0) se[wid] = s;
    }
}

// ---------------------------------------------------------------------------
// K1: partial argmin. Grid (256 row-tiles, 4 code-chunks). Each block:
// 64 rows x 1024 codes, fp32 vector GEMM, BM=64 BN=128 BK=32, 512 thr, 4x4.
// NO union (R2/R3 lesson: union-typed LDS access scalarized the float4
// ds_read_b128 into 4-way-conflicted b32 reads -> 4.2e8 conflict cycles).
// Argmin reduction via shfl_xor butterfly (LDS handoff only 512B).
// Plain __launch_bounds__(512): R0's known-good 60-VGPR codegen.
// ---------------------------------------------------------------------------
__global__ __launch_bounds__(512) void argmin_kernel(
        const float* __restrict__ z, const float* __restrict__ W,
        const float* __restrict__ se,
        float* __restrict__ bDw, int* __restrict__ bIw) {
    __shared__ float As[32][64];    //  8 KB
    __shared__ float Bs[32][128];   // 16 KB
    __shared__ float szp[4][64];
    __shared__ float sz_s[64];
    __shared__ float rD[64];
    __shared__ int   rI[64];

    const int tid   = threadIdx.x;
    const int r0    = blockIdx.x * 64;        // first row of tile
    const int chunk = blockIdx.y;             // code chunk
    const int bb    = r0 >> 13;               // batch index
    const int sp0   = r0 & (SPAT - 1);        // spatial base (multiple of 64)
    const float* zb = z + (size_t)bb * (EDIM * SPAT) + sp0;

    // row norms: 256 threads, 4 k-chunks of 64 each
    if (tid < 256) {
        int lr = tid & 63, kq = tid >> 6;
        float s = 0.f;
        const float* p = zb + lr + (size_t)(kq * 64) * SPAT;
        for (int k = 0; k < 64; ++k) {
            float v = p[(size_t)k * SPAT];
            s += v * v;
        }
        szp[kq][lr] = s;
    }
    __syncthreads();
    if (tid < 64)
        sz_s[tid] = ((szp[0][tid] + szp[1][tid]) + szp[2][tid]) + szp[3][tid];
    // (visibility of sz_s guaranteed by the first barrier inside the k0 loop)

    const int rg = tid >> 5;          // 0..15 -> rows rg*4..+3
    const int cg = tid & 31;          // 0..31 -> cols cg*4..+3 within chunk
    const int a_kk = tid >> 4;              // 0..31
    const int a_lr = (tid & 15) << 2;       // 0,4,..,60
    const int b_lc = tid & 127;             // 0..127
    const int b_kq = tid >> 7;              // 0..3

    float bestD[4];
    int   bestI[4];
    #pragma unroll
    for (int i = 0; i < 4; ++i) { bestD[i] = 3.4e38f; bestI[i] = 0; }

    const int cbeg = chunk * CHUNKC;
    for (int c0 = cbeg; c0 < cbeg + CHUNKC; c0 += 128) {
        float acc[4][4];
        #pragma unroll
        for (int i = 0; i < 4; ++i)
            #pragma unroll
            for (int j = 0; j < 4; ++j) acc[i][j] = 0.f;

        for (int k0 = 0; k0 < EDIM; k0 += 32) {
            __syncthreads();   // previous iter's LDS reads done
            const float4 av = *(const float4*)(zb + (size_t)(k0 + a_kk) * SPAT + a_lr);
            *(float4*)&As[a_kk][a_lr] = av;
            #pragma unroll
            for (int t = 0; t < 2; ++t) {
                int kk = b_kq * 8 + t * 4;
                const float4 bv = *(const float4*)(W + (size_t)(c0 + b_lc) * EDIM + k0 + kk);
                Bs[kk + 0][b_lc] = bv.x;
                Bs[kk + 1][b_lc] = bv.y;
                Bs[kk + 2][b_lc] = bv.z;
                Bs[kk + 3][b_lc] = bv.w;
            }
            __syncthreads();
            #pragma unroll
            for (int kk = 0; kk < 32; ++kk) {
                const float4 a = *(const float4*)&As[kk][rg << 2];
                const float4 b = *(const float4*)&Bs[kk][cg << 2];
                acc[0][0] += a.x * b.x; acc[0][1] += a.x * b.y;
                acc[0][2] += a.x * b.z; acc[0][3] += a.x * b.w;
                acc[1][0] += a.y * b.x; acc[1][1] += a.y * b.y;
                acc[1][2] += a.y * b.z; acc[1][3] += a.y * b.w;
                acc[2][0] += a.z * b.x; acc[2][1] += a.z * b.y;
                acc[2][2] += a.z * b.z; acc[2][3] += a.z * b.w;
                acc[3][0] += a.w * b.x; acc[3][1] += a.w * b.y;
                acc[3][2] += a.w * b.z; acc[3][3] += a.w * b.w;
            }
        }
        // distances + running argmin (codes ascend => first-min kept)
        #pragma unroll
        for (int i = 0; i < 4; ++i) {
            const float szr = sz_s[(rg << 2) + i];
            #pragma unroll
            for (int j = 0; j < 4; ++j) {
                const int code = c0 + (cg << 2) + j;
                const float d = (szr + se[code]) - 2.0f * acc[i][j];
                if (d < bestD[i]) { bestD[i] = d; bestI[i] = code; }
            }
        }
    }

    // shfl_xor butterfly across the 32-lane column group (masks <=16 stay
    // inside each half-wave; all lanes of a half share the same 4 rows)
    #pragma unroll
    for (int mask = 16; mask > 0; mask >>= 1) {
        #pragma unroll
        for (int i = 0; i < 4; ++i) {
            const float od = __shfl_xor(bestD[i], mask);
            const int   oi = __shfl_xor(bestI[i], mask);
            if (od < bestD[i] || (od == bestD[i] && oi < bestI[i])) {
                bestD[i] = od; bestI[i] = oi;
            }
        }
    }
    if (cg == 0) {
        #pragma unroll
        for (int i = 0; i < 4; ++i) {
            rD[(rg << 2) + i] = bestD[i];
            rI[(rg << 2) + i] = bestI[i];
        }
    }
    __syncthreads();
    if (tid < 64) {
        bDw[chunk * NROWS + r0 + tid] = rD[tid];
        bIw[chunk * NROWS + r0 + tid] = rI[tid];
    }
}

// ---------------------------------------------------------------------------
// K1b: combine partial argmins + write one-hot rows (zeros AND ones, fused,
// replaces the 256MB memset). One wave per row.
// ---------------------------------------------------------------------------
__global__ __launch_bounds__(256) void combine_kernel(
        const float* __restrict__ bDw, const int* __restrict__ bIw,
        int* __restrict__ idx_ws, int* __restrict__ counts,
        float* __restrict__ out_idx, float* __restrict__ out_onehot) {
    const int g    = blockIdx.x * 256 + threadIdx.x;
    const int row  = g >> 6;          // wave-per-row
    const int lane = g & 63;

    float d0 = bDw[row];
    int   i0 = bIw[row];
    #pragma unroll
    for (int c = 1; c < NCHUNK; ++c) {
        const float d  = bDw[c * NROWS + row];
        const int   ii = bIw[c * NROWS + row];
        if (d < d0 || (d == d0 && ii < i0)) { d0 = d; i0 = ii; }
    }
    if (lane == 0) {
        idx_ws[row]  = i0;
        out_idx[row] = (float)i0;
        atomicAdd(&counts[i0], 1);
    }
    float* dst = out_onehot + (size_t)row * N_E;
    #pragma unroll
    for (int w = 0; w < 16; ++w) {
        const int cb = w * 256 + lane * 4;
        float4 v;
        v.x = (cb + 0 == i0) ? 1.0f : 0.0f;
        v.y = (cb + 1 == i0) ? 1.0f : 0.0f;
        v.z = (cb + 2 == i0) ? 1.0f : 0.0f;
        v.w = (cb + 3 == i0) ? 1.0f : 0.0f;
        *(float4*)(dst + cb) = v;
    }
}

// ---------------------------------------------------------------------------
// K2: z_q_out, z_out, loss partial sums
// ---------------------------------------------------------------------------
__global__ __launch_bounds__(256) void outputs_kernel(
        const float* __restrict__ z, const float* __restrict__ W,
        const int* __restrict__ idx,
        float* __restrict__ zq_out, float* __restrict__ z_out,
        double* __restrict__ loss_acc) {
    const int t  = blockIdx.x * 256 + threadIdx.x;     // 0..ZELEMS-1
    const float zv = z[t];
    const int sp = t & (SPAT - 1);
    const int c  = (t >> 13) & 255;
    const int b  = t >> 21;
    const int n  = (b << 13) + sp;
    const int id = idx[n];
    const float e    = W[id * EDIM + c];
    const float diff = e - zv;        // z_q - zp
    zq_out[t] = zv + diff;            // straight-through value, exact rounding
    z_out[t]  = zv;

    double ds = (double)(diff * diff);
    #pragma unroll
    for (int off = 32; off > 0; off >>= 1) ds += __shfl_down(ds, off);
    __shared__ double bsum[4];
    const int lane = threadIdx.x & 63, w = threadIdx.x >> 6;
    if (lane == 0) bsum[w] = ds;
    __syncthreads();
    if (threadIdx.x == 0)
        atomicAdd(loss_acc, bsum[0] + bsum[1] + bsum[2] + bsum[3]);
}

// ---------------------------------------------------------------------------
// K3: EMA buffer update
// ---------------------------------------------------------------------------
__global__ __launch_bounds__(256) void ema_kernel(const float* __restrict__ W,
                                                  const float* __restrict__ ema,
                                                  float* __restrict__ out) {
    const int t = blockIdx.x * 256 + threadIdx.x;   // 0..1048575
    out[t] = 0.25f * ema[t] + 0.75f * W[t];
}

// ---------------------------------------------------------------------------
// K4: perplexity + loss finalize (single block)
// ---------------------------------------------------------------------------
__global__ __launch_bounds__(256) void final_kernel(
        const int* __restrict__ counts, const double* __restrict__ loss_acc,
        float* __restrict__ out_loss, float* __restrict__ out_perp) {
    __shared__ float ps[256];
    float s = 0.f;
    for (int c = threadIdx.x; c < N_E; c += 256) {
        const float p = (float)counts[c] * (1.0f / (float)NROWS);
        s += p * logf(p + 1e-10f);
    }
    ps[threadIdx.x] = s;
    __syncthreads();
    for (int off = 128; off > 0; off >>= 1) {
        if (threadIdx.x < off) ps[threadIdx.x] += ps[threadIdx.x + off];
        __syncthreads();
    }
    if (threadIdx.x == 0) {
        *out_perp = expf(-ps[0]);
        const float m = (float)(*loss_acc / (double)ZELEMS);
        *out_loss = m + 0.25f * m;
    }
}

// ---------------------------------------------------------------------------
extern "C" void kernel_launch(void* const* d_in, const int* in_sizes, int n_in,
                              void* d_out, int out_size, void* d_ws, size_t ws_size,
                              hipStream_t stream) {
    const float* z   = (const float*)d_in[0];
    const float* W   = (const float*)d_in[1];
    const float* ema = (const float*)d_in[2];
    float* out = (float*)d_out;

    float* out_loss   = out + OFF_LOSS;
    float* out_zq     = out + OFF_ZQ;
    float* out_perp   = out + OFF_PERP;
    float* out_onehot = out + OFF_ONEHOT;
    float* out_idx    = out + OFF_IDX;
    float* out_z      = out + OFF_ZOUT;
    float* out_ema    = out + OFF_EMA;

    // workspace layout
    char* ws = (char*)d_ws;
    double* loss_acc = (double*)ws;                        // 16 B
    int*    counts   = (int*)(ws + 16);                    // 16 KB
    int*    idxb     = (int*)(ws + 16 + 16384);            // 64 KB
    float*  se       = (float*)(ws + 16 + 16384 + 65536);  // 16 KB
    float*  bDw      = (float*)(ws + 16 + 16384 + 65536 + 16384);           // 256 KB
    int*    bIw      = (int*)  (ws + 16 + 16384 + 65536 + 16384 + 262144);  // 256 KB

    hipMemsetAsync(d_ws, 0, 16 + 16384, stream);   // loss + counts

    se_kernel<<<1024, 256, 0, stream>>>(W, se);
    argmin_kernel<<<dim3(NROWS / 64, NCHUNK), 512, 0, stream>>>(z, W, se, bDw, bIw);
    combine_kernel<<<NROWS * 64 / 256, 256, 0, stream>>>(bDw, bIw, idxb, counts,
                                                         out_idx, out_onehot);
    outputs_kernel<<<ZELEMS / 256, 256, 0, stream>>>(z, W, idxb, out_zq, out_z,
                                                     loss_acc);
    ema_kernel<<<(N_E * EDIM) / 256, 256, 0, stream>>>(W, ema, out_ema);
    final_kernel<<<1, 256, 0, stream>>>(counts, loss_acc, out_loss, out_perp);
}

// Round 5
// 841.004 us; speedup vs baseline: 2.0931x; 1.1827x over previous
//
#include <hip/hip_runtime.h>
#include <hip/hip_bf16.h>
#include <math.h>

// Problem constants
#define N_E    4096      // number of codes
#define EDIM   256       // embedding dim (K)
#define SPAT   8192      // 8*32*32 spatial per (b,c)
#define NROWS  16384     // NB * SPAT flattened rows
#define ZELEMS 4194304   // 2*256*8*32*32
#define NCHUNK 4         // code-dim split for occupancy
#define CHUNKC 1024      // codes per chunk
#define NLOSSPARTS 16384 // outputs_kernel grid size

// Output offsets (flat float32 in return order)
#define OFF_LOSS    0
#define OFF_ZQ      1
#define OFF_PERP    4194305
#define OFF_ONEHOT  4194306
#define OFF_IDX     71303170
#define OFF_ZOUT    71319554
#define OFF_EMA     75513858

// ---------------------------------------------------------------------------
// K0: se[c] = sum_k W[c][k]^2   (one wave per code)
// ---------------------------------------------------------------------------
__global__ __launch_bounds__(256) void se_kernel(const float* __restrict__ W,
                                                 float* __restrict__ se) {
    int wid  = (blockIdx.x * 256 + threadIdx.x) >> 6;   // wave id = code id
    int lane = threadIdx.x & 63;
    if (wid < N_E) {
        const float4 v = *(const float4*)(W + (size_t)wid * EDIM + lane * 4);
        float s = v.x * v.x + v.y * v.y + v.z * v.z + v.w * v.w;
        #pragma unroll
        for (int off = 32; off > 0; off >>= 1) s += __shfl_down(s, off);
        if (lane == 0) se[wid] = s;
    }
}

// ---------------------------------------------------------------------------
// K1: partial argmin. Grid (256 row-tiles, 4 code-chunks). Each block:
// 64 rows x 1024 codes, fp32 vector GEMM, BM=64 BN=128 BK=32, 512 thr, 4x4.
// NO union (R2/R3 lesson: union-typed LDS access scalarized the float4
// ds_read_b128 into 4-way-conflicted b32 reads -> 4.2e8 conflict cycles).
// Argmin reduction via shfl_xor butterfly (LDS handoff only 512B).
// Plain __launch_bounds__(512): R0's known-good 60-VGPR codegen.
// ---------------------------------------------------------------------------
__global__ __launch_bounds__(512) void argmin_kernel(
        const float* __restrict__ z, const float* __restrict__ W,
        const float* __restrict__ se,
        float* __restrict__ bDw, int* __restrict__ bIw) {
    __shared__ float As[32][64];    //  8 KB
    __shared__ float Bs[32][128];   // 16 KB
    __shared__ float szp[4][64];
    __shared__ float sz_s[64];
    __shared__ float rD[64];
    __shared__ int   rI[64];

    const int tid   = threadIdx.x;
    const int r0    = blockIdx.x * 64;        // first row of tile
    const int chunk = blockIdx.y;             // code chunk
    const int bb    = r0 >> 13;               // batch index
    const int sp0   = r0 & (SPAT - 1);        // spatial base (multiple of 64)
    const float* zb = z + (size_t)bb * (EDIM * SPAT) + sp0;

    // row norms: 256 threads, 4 k-chunks of 64 each
    if (tid < 256) {
        int lr = tid & 63, kq = tid >> 6;
        float s = 0.f;
        const float* p = zb + lr + (size_t)(kq * 64) * SPAT;
        for (int k = 0; k < 64; ++k) {
            float v = p[(size_t)k * SPAT];
            s += v * v;
        }
        szp[kq][lr] = s;
    }
    __syncthreads();
    if (tid < 64)
        sz_s[tid] = ((szp[0][tid] + szp[1][tid]) + szp[2][tid]) + szp[3][tid];
    // (visibility of sz_s guaranteed by the first barrier inside the k0 loop)

    const int rg = tid >> 5;          // 0..15 -> rows rg*4..+3
    const int cg = tid & 31;          // 0..31 -> cols cg*4..+3 within chunk
    const int a_kk = tid >> 4;              // 0..31
    const int a_lr = (tid & 15) << 2;       // 0,4,..,60
    const int b_lc = tid & 127;             // 0..127
    const int b_kq = tid >> 7;              // 0..3

    float bestD[4];
    int   bestI[4];
    #pragma unroll
    for (int i = 0; i < 4; ++i) { bestD[i] = 3.4e38f; bestI[i] = 0; }

    const int cbeg = chunk * CHUNKC;
    for (int c0 = cbeg; c0 < cbeg + CHUNKC; c0 += 128) {
        float acc[4][4];
        #pragma unroll
        for (int i = 0; i < 4; ++i)
            #pragma unroll
            for (int j = 0; j < 4; ++j) acc[i][j] = 0.f;

        for (int k0 = 0; k0 < EDIM; k0 += 32) {
            __syncthreads();   // previous iter's LDS reads done
            const float4 av = *(const float4*)(zb + (size_t)(k0 + a_kk) * SPAT + a_lr);
            *(float4*)&As[a_kk][a_lr] = av;
            #pragma unroll
            for (int t = 0; t < 2; ++t) {
                int kk = b_kq * 8 + t * 4;
                const float4 bv = *(const float4*)(W + (size_t)(c0 + b_lc) * EDIM + k0 + kk);
                Bs[kk + 0][b_lc] = bv.x;
                Bs[kk + 1][b_lc] = bv.y;
                Bs[kk + 2][b_lc] = bv.z;
                Bs[kk + 3][b_lc] = bv.w;
            }
            __syncthreads();
            #pragma unroll
            for (int kk = 0; kk < 32; ++kk) {
                const float4 a = *(const float4*)&As[kk][rg << 2];
                const float4 b = *(const float4*)&Bs[kk][cg << 2];
                acc[0][0] += a.x * b.x; acc[0][1] += a.x * b.y;
                acc[0][2] += a.x * b.z; acc[0][3] += a.x * b.w;
                acc[1][0] += a.y * b.x; acc[1][1] += a.y * b.y;
                acc[1][2] += a.y * b.z; acc[1][3] += a.y * b.w;
                acc[2][0] += a.z * b.x; acc[2][1] += a.z * b.y;
                acc[2][2] += a.z * b.z; acc[2][3] += a.z * b.w;
                acc[3][0] += a.w * b.x; acc[3][1] += a.w * b.y;
                acc[3][2] += a.w * b.z; acc[3][3] += a.w * b.w;
            }
        }
        // distances + running argmin (codes ascend => first-min kept)
        #pragma unroll
        for (int i = 0; i < 4; ++i) {
            const float szr = sz_s[(rg << 2) + i];
            #pragma unroll
            for (int j = 0; j < 4; ++j) {
                const int code = c0 + (cg << 2) + j;
                const float d = (szr + se[code]) - 2.0f * acc[i][j];
                if (d < bestD[i]) { bestD[i] = d; bestI[i] = code; }
            }
        }
    }

    // shfl_xor butterfly across the 32-lane column group (masks <=16 stay
    // inside each half-wave; all lanes of a half share the same 4 rows)
    #pragma unroll
    for (int mask = 16; mask > 0; mask >>= 1) {
        #pragma unroll
        for (int i = 0; i < 4; ++i) {
            const float od = __shfl_xor(bestD[i], mask);
            const int   oi = __shfl_xor(bestI[i], mask);
            if (od < bestD[i] || (od == bestD[i] && oi < bestI[i])) {
                bestD[i] = od; bestI[i] = oi;
            }
        }
    }
    if (cg == 0) {
        #pragma unroll
        for (int i = 0; i < 4; ++i) {
            rD[(rg << 2) + i] = bestD[i];
            rI[(rg << 2) + i] = bestI[i];
        }
    }
    __syncthreads();
    if (tid < 64) {
        bDw[chunk * NROWS + r0 + tid] = rD[tid];
        bIw[chunk * NROWS + r0 + tid] = rI[tid];
    }
}

// ---------------------------------------------------------------------------
// K1b: combine partial argmins + write one-hot rows (zeros AND ones, fused,
// replaces the 256MB memset). One wave per row.
// ---------------------------------------------------------------------------
__global__ __launch_bounds__(256) void combine_kernel(
        const float* __restrict__ bDw, const int* __restrict__ bIw,
        int* __restrict__ idx_ws, int* __restrict__ counts,
        float* __restrict__ out_idx, float* __restrict__ out_onehot) {
    const int g    = blockIdx.x * 256 + threadIdx.x;
    const int row  = g >> 6;          // wave-per-row
    const int lane = g & 63;

    float d0 = bDw[row];
    int   i0 = bIw[row];
    #pragma unroll
    for (int c = 1; c < NCHUNK; ++c) {
        const float d  = bDw[c * NROWS + row];
        const int   ii = bIw[c * NROWS + row];
        if (d < d0 || (d == d0 && ii < i0)) { d0 = d; i0 = ii; }
    }
    if (lane == 0) {
        idx_ws[row]  = i0;
        out_idx[row] = (float)i0;
        atomicAdd(&counts[i0], 1);
    }
    float* dst = out_onehot + (size_t)row * N_E;
    #pragma unroll
    for (int w = 0; w < 16; ++w) {
        const int cb = w * 256 + lane * 4;
        float4 v;
        v.x = (cb + 0 == i0) ? 1.0f : 0.0f;
        v.y = (cb + 1 == i0) ? 1.0f : 0.0f;
        v.z = (cb + 2 == i0) ? 1.0f : 0.0f;
        v.w = (cb + 3 == i0) ? 1.0f : 0.0f;
        *(float4*)(dst + cb) = v;
    }
}

// ---------------------------------------------------------------------------
// K2: z_q_out, z_out, loss partials. R4 lesson candidate: the single-address
// f64 atomicAdd from 16384 blocks serialized (~350us hidden). Now each block
// writes its own partial slot; final_kernel sums them.
// ---------------------------------------------------------------------------
__global__ __launch_bounds__(256) void outputs_kernel(
        const float* __restrict__ z, const float* __restrict__ W,
        const int* __restrict__ idx,
        float* __restrict__ zq_out, float* __restrict__ z_out,
        double* __restrict__ loss_parts) {
    const int t  = blockIdx.x * 256 + threadIdx.x;     // 0..ZELEMS-1
    const float zv = z[t];
    const int sp = t & (SPAT - 1);
    const int c  = (t >> 13) & 255;
    const int b  = t >> 21;
    const int n  = (b << 13) + sp;
    const int id = idx[n];
    const float e    = W[id * EDIM + c];
    const float diff = e - zv;        // z_q - zp
    zq_out[t] = zv + diff;            // straight-through value, exact rounding
    z_out[t]  = zv;

    double ds = (double)(diff * diff);
    #pragma unroll
    for (int off = 32; off > 0; off >>= 1) ds += __shfl_down(ds, off);
    __shared__ double bsum[4];
    const int lane = threadIdx.x & 63, w = threadIdx.x >> 6;
    if (lane == 0) bsum[w] = ds;
    __syncthreads();
    if (threadIdx.x == 0)
        loss_parts[blockIdx.x] = bsum[0] + bsum[1] + bsum[2] + bsum[3];
}

// ---------------------------------------------------------------------------
// K3: EMA buffer update
// ---------------------------------------------------------------------------
__global__ __launch_bounds__(256) void ema_kernel(const float* __restrict__ W,
                                                  const float* __restrict__ ema,
                                                  float* __restrict__ out) {
    const int t = blockIdx.x * 256 + threadIdx.x;   // 0..1048575
    out[t] = 0.25f * ema[t] + 0.75f * W[t];
}

// ---------------------------------------------------------------------------
// K4: perplexity + loss finalize (single block)
// ---------------------------------------------------------------------------
__global__ __launch_bounds__(256) void final_kernel(
        const int* __restrict__ counts, const double* __restrict__ loss_parts,
        float* __restrict__ out_loss, float* __restrict__ out_perp) {
    __shared__ float ps[256];
    __shared__ double ls[256];
    float s = 0.f;
    for (int c = threadIdx.x; c < N_E; c += 256) {
        const float p = (float)counts[c] * (1.0f / (float)NROWS);
        s += p * logf(p + 1e-10f);
    }
    double l = 0.0;
    for (int c = threadIdx.x; c < NLOSSPARTS; c += 256) l += loss_parts[c];
    ps[threadIdx.x] = s;
    ls[threadIdx.x] = l;
    __syncthreads();
    for (int off = 128; off > 0; off >>= 1) {
        if (threadIdx.x < off) {
            ps[threadIdx.x] += ps[threadIdx.x + off];
            ls[threadIdx.x] += ls[threadIdx.x + off];
        }
        __syncthreads();
    }
    if (threadIdx.x == 0) {
        *out_perp = expf(-ps[0]);
        const float m = (float)(ls[0] / (double)ZELEMS);
        *out_loss = m + 0.25f * m;
    }
}

// ---------------------------------------------------------------------------
extern "C" void kernel_launch(void* const* d_in, const int* in_sizes, int n_in,
                              void* d_out, int out_size, void* d_ws, size_t ws_size,
                              hipStream_t stream) {
    const float* z   = (const float*)d_in[0];
    const float* W   = (const float*)d_in[1];
    const float* ema = (const float*)d_in[2];
    float* out = (float*)d_out;

    float* out_loss   = out + OFF_LOSS;
    float* out_zq     = out + OFF_ZQ;
    float* out_perp   = out + OFF_PERP;
    float* out_onehot = out + OFF_ONEHOT;
    float* out_idx    = out + OFF_IDX;
    float* out_z      = out + OFF_ZOUT;
    float* out_ema    = out + OFF_EMA;

    // workspace layout
    char* ws = (char*)d_ws;
    int*    counts   = (int*)ws;                            // 16 KB
    int*    idxb     = (int*)(ws + 16384);                  // 64 KB
    float*  se       = (float*)(ws + 16384 + 65536);        // 16 KB
    float*  bDw      = (float*)(ws + 98304);                // 256 KB
    int*    bIw      = (int*)  (ws + 98304 + 262144);       // 256 KB
    double* lossp    = (double*)(ws + 98304 + 524288);      // 128 KB (all slots written)

    hipMemsetAsync(counts, 0, 16384, stream);   // counts only

    se_kernel<<<1024, 256, 0, stream>>>(W, se);
    argmin_kernel<<<dim3(NROWS / 64, NCHUNK), 512, 0, stream>>>(z, W, se, bDw, bIw);
    combine_kernel<<<NROWS * 64 / 256, 256, 0, stream>>>(bDw, bIw, idxb, counts,
                                                         out_idx, out_onehot);
    outputs_kernel<<<ZELEMS / 256, 256, 0, stream>>>(z, W, idxb, out_zq, out_z,
                                                     lossp);
    ema_kernel<<<(N_E * EDIM) / 256, 256, 0, stream>>>(W, ema, out_ema);
    final_kernel<<<1, 256, 0, stream>>>(counts, lossp, out_loss, out_perp);
}

// Round 6
// 806.707 us; speedup vs baseline: 2.1821x; 1.0425x over previous
//
#include <hip/hip_runtime.h>
#include <hip/hip_bf16.h>
#include <math.h>

// Problem constants
#define N_E    4096      // number of codes
#define EDIM   256       // embedding dim (K)
#define SPAT   8192      // 8*32*32 spatial per (b,c)
#define NROWS  16384     // NB * SPAT flattened rows
#define ZELEMS 4194304   // 2*256*8*32*32
#define NCHUNK 4         // code-dim split for occupancy
#define CHUNKC 1024      // codes per chunk
#define NLOSSPARTS 16384 // outputs_kernel grid size

// Output offsets (flat float32 in return order)
#define OFF_LOSS    0
#define OFF_ZQ      1
#define OFF_PERP    4194305
#define OFF_ONEHOT  4194306
#define OFF_IDX     71303170
#define OFF_ZOUT    71319554
#define OFF_EMA     75513858

// ---------------------------------------------------------------------------
// K0: se[c] = sum_k W[c][k]^2   (one wave per code)
// ---------------------------------------------------------------------------
__global__ __launch_bounds__(256) void se_kernel(const float* __restrict__ W,
                                                 float* __restrict__ se) {
    int wid  = (blockIdx.x * 256 + threadIdx.x) >> 6;   // wave id = code id
    int lane = threadIdx.x & 63;
    if (wid < N_E) {
        const float4 v = *(const float4*)(W + (size_t)wid * EDIM + lane * 4);
        float s = v.x * v.x + v.y * v.y + v.z * v.z + v.w * v.w;
        #pragma unroll
        for (int off = 32; off > 0; off >>= 1) s += __shfl_down(s, off);
        if (lane == 0) se[wid] = s;
    }
}

// ---------------------------------------------------------------------------
// K1: partial argmin. Grid (128 row-tiles, 4 code-chunks). Each block:
// 128 rows x 1024 codes, fp32 vector GEMM, BM=128 BN=128 BK=32, 512 thr,
// 8x4 micro-tile (R5 lesson: 4x4 demanded 64 B/cyc/CU LDS vs 85 ceiling ->
// VALUBusy capped at 58%; 8x4 needs only 48 B/cyc and A-reads broadcast).
// NO union (R2/R3: union-typed LDS scalarizes ds_read_b128 -> conflicts).
// (512,4): VGPR cap 128 (R3 proved this bound itself is benign).
// ---------------------------------------------------------------------------
__global__ __launch_bounds__(512, 4) void argmin_kernel(
        const float* __restrict__ z, const float* __restrict__ W,
        const float* __restrict__ se,
        float* __restrict__ bDw, int* __restrict__ bIw) {
    __shared__ float As[32][128];   // 16 KB
    __shared__ float Bs[32][128];   // 16 KB
    __shared__ float szp[4][128];
    __shared__ float sz_s[128];
    __shared__ float rD[128];
    __shared__ int   rI[128];

    const int tid   = threadIdx.x;
    const int r0    = blockIdx.x * 128;       // first row of tile
    const int chunk = blockIdx.y;             // code chunk
    const int bb    = r0 >> 13;               // batch index
    const int sp0   = r0 & (SPAT - 1);        // spatial base (multiple of 128)
    const float* zb = z + (size_t)bb * (EDIM * SPAT) + sp0;

    // row norms: 512 threads, 4 k-chunks of 64 each over 128 rows
    {
        const int lr = tid & 127, kq = tid >> 7;
        float s = 0.f;
        const float* p = zb + lr + (size_t)(kq * 64) * SPAT;
        for (int k = 0; k < 64; ++k) {
            float v = p[(size_t)k * SPAT];
            s += v * v;
        }
        szp[kq][lr] = s;
    }
    __syncthreads();
    if (tid < 128)
        sz_s[tid] = ((szp[0][tid] + szp[1][tid]) + szp[2][tid]) + szp[3][tid];
    // (visibility of sz_s guaranteed by the first barrier inside the k0 loop)

    const int rg = tid >> 5;          // 0..15 -> rows rg*8..+7
    const int cg = tid & 31;          // 0..31 -> cols cg*4..+3 within tile
    const int a_kk = tid >> 4;              // 0..31
    const int a_lr = (tid & 15) << 3;       // 0,8,..,120
    const int b_lc = tid & 127;             // 0..127
    const int b_kq = tid >> 7;              // 0..3

    float bestD[8];
    int   bestI[8];
    #pragma unroll
    for (int i = 0; i < 8; ++i) { bestD[i] = 3.4e38f; bestI[i] = 0; }

    const int cbeg = chunk * CHUNKC;
    for (int c0 = cbeg; c0 < cbeg + CHUNKC; c0 += 128) {
        float acc[8][4];
        #pragma unroll
        for (int i = 0; i < 8; ++i)
            #pragma unroll
            for (int j = 0; j < 4; ++j) acc[i][j] = 0.f;

        for (int k0 = 0; k0 < EDIM; k0 += 32) {
            __syncthreads();   // previous iter's LDS reads done
            const float4 av0 = *(const float4*)(zb + (size_t)(k0 + a_kk) * SPAT + a_lr);
            const float4 av1 = *(const float4*)(zb + (size_t)(k0 + a_kk) * SPAT + a_lr + 4);
            *(float4*)&As[a_kk][a_lr]     = av0;
            *(float4*)&As[a_kk][a_lr + 4] = av1;
            #pragma unroll
            for (int t = 0; t < 2; ++t) {
                int kk = b_kq * 8 + t * 4;
                const float4 bv = *(const float4*)(W + (size_t)(c0 + b_lc) * EDIM + k0 + kk);
                Bs[kk + 0][b_lc] = bv.x;
                Bs[kk + 1][b_lc] = bv.y;
                Bs[kk + 2][b_lc] = bv.z;
                Bs[kk + 3][b_lc] = bv.w;
            }
            __syncthreads();
            #pragma unroll
            for (int kk = 0; kk < 32; ++kk) {
                const float4 a0 = *(const float4*)&As[kk][rg << 3];
                const float4 a1 = *(const float4*)&As[kk][(rg << 3) + 4];
                const float4 b  = *(const float4*)&Bs[kk][cg << 2];
                acc[0][0] += a0.x * b.x; acc[0][1] += a0.x * b.y;
                acc[0][2] += a0.x * b.z; acc[0][3] += a0.x * b.w;
                acc[1][0] += a0.y * b.x; acc[1][1] += a0.y * b.y;
                acc[1][2] += a0.y * b.z; acc[1][3] += a0.y * b.w;
                acc[2][0] += a0.z * b.x; acc[2][1] += a0.z * b.y;
                acc[2][2] += a0.z * b.z; acc[2][3] += a0.z * b.w;
                acc[3][0] += a0.w * b.x; acc[3][1] += a0.w * b.y;
                acc[3][2] += a0.w * b.z; acc[3][3] += a0.w * b.w;
                acc[4][0] += a1.x * b.x; acc[4][1] += a1.x * b.y;
                acc[4][2] += a1.x * b.z; acc[4][3] += a1.x * b.w;
                acc[5][0] += a1.y * b.x; acc[5][1] += a1.y * b.y;
                acc[5][2] += a1.y * b.z; acc[5][3] += a1.y * b.w;
                acc[6][0] += a1.z * b.x; acc[6][1] += a1.z * b.y;
                acc[6][2] += a1.z * b.z; acc[6][3] += a1.z * b.w;
                acc[7][0] += a1.w * b.x; acc[7][1] += a1.w * b.y;
                acc[7][2] += a1.w * b.z; acc[7][3] += a1.w * b.w;
            }
        }
        // distances + running argmin (codes ascend => first-min kept)
        #pragma unroll
        for (int i = 0; i < 8; ++i) {
            const float szr = sz_s[(rg << 3) + i];
            #pragma unroll
            for (int j = 0; j < 4; ++j) {
                const int code = c0 + (cg << 2) + j;
                const float d = (szr + se[code]) - 2.0f * acc[i][j];
                if (d < bestD[i]) { bestD[i] = d; bestI[i] = code; }
            }
        }
    }

    // shfl_xor butterfly across the 32-lane column group (masks <=16 stay
    // inside each half-wave; all lanes of a half share the same 8 rows)
    #pragma unroll
    for (int mask = 16; mask > 0; mask >>= 1) {
        #pragma unroll
        for (int i = 0; i < 8; ++i) {
            const float od = __shfl_xor(bestD[i], mask);
            const int   oi = __shfl_xor(bestI[i], mask);
            if (od < bestD[i] || (od == bestD[i] && oi < bestI[i])) {
                bestD[i] = od; bestI[i] = oi;
            }
        }
    }
    if (cg == 0) {
        #pragma unroll
        for (int i = 0; i < 8; ++i) {
            rD[(rg << 3) + i] = bestD[i];
            rI[(rg << 3) + i] = bestI[i];
        }
    }
    __syncthreads();
    if (tid < 128) {
        bDw[chunk * NROWS + r0 + tid] = rD[tid];
        bIw[chunk * NROWS + r0 + tid] = rI[tid];
    }
}

// ---------------------------------------------------------------------------
// K1b: combine partial argmins + write one-hot rows (zeros AND ones, fused,
// replaces the 256MB memset). One wave per row.
// ---------------------------------------------------------------------------
__global__ __launch_bounds__(256) void combine_kernel(
        const float* __restrict__ bDw, const int* __restrict__ bIw,
        int* __restrict__ idx_ws, int* __restrict__ counts,
        float* __restrict__ out_idx, float* __restrict__ out_onehot) {
    const int g    = blockIdx.x * 256 + threadIdx.x;
    const int row  = g >> 6;          // wave-per-row
    const int lane = g & 63;

    float d0 = bDw[row];
    int   i0 = bIw[row];
    #pragma unroll
    for (int c = 1; c < NCHUNK; ++c) {
        const float d  = bDw[c * NROWS + row];
        const int   ii = bIw[c * NROWS + row];
        if (d < d0 || (d == d0 && ii < i0)) { d0 = d; i0 = ii; }
    }
    if (lane == 0) {
        idx_ws[row]  = i0;
        out_idx[row] = (float)i0;
        atomicAdd(&counts[i0], 1);
    }
    float* dst = out_onehot + (size_t)row * N_E;
    #pragma unroll
    for (int w = 0; w < 16; ++w) {
        const int cb = w * 256 + lane * 4;
        float4 v;
        v.x = (cb + 0 == i0) ? 1.0f : 0.0f;
        v.y = (cb + 1 == i0) ? 1.0f : 0.0f;
        v.z = (cb + 2 == i0) ? 1.0f : 0.0f;
        v.w = (cb + 3 == i0) ? 1.0f : 0.0f;
        *(float4*)(dst + cb) = v;
    }
}

// ---------------------------------------------------------------------------
// K2: z_q_out, z_out, loss partials (per-block slots; R5: single-address
// f64 atomic from 16384 blocks serialized ~150us).
// ---------------------------------------------------------------------------
__global__ __launch_bounds__(256) void outputs_kernel(
        const float* __restrict__ z, const float* __restrict__ W,
        const int* __restrict__ idx,
        float* __restrict__ zq_out, float* __restrict__ z_out,
        double* __restrict__ loss_parts) {
    const int t  = blockIdx.x * 256 + threadIdx.x;     // 0..ZELEMS-1
    const float zv = z[t];
    const int sp = t & (SPAT - 1);
    const int c  = (t >> 13) & 255;
    const int b  = t >> 21;
    const int n  = (b << 13) + sp;
    const int id = idx[n];
    const float e    = W[id * EDIM + c];
    const float diff = e - zv;        // z_q - zp
    zq_out[t] = zv + diff;            // straight-through value, exact rounding
    z_out[t]  = zv;

    double ds = (double)(diff * diff);
    #pragma unroll
    for (int off = 32; off > 0; off >>= 1) ds += __shfl_down(ds, off);
    __shared__ double bsum[4];
    const int lane = threadIdx.x & 63, w = threadIdx.x >> 6;
    if (lane == 0) bsum[w] = ds;
    __syncthreads();
    if (threadIdx.x == 0)
        loss_parts[blockIdx.x] = bsum[0] + bsum[1] + bsum[2] + bsum[3];
}

// ---------------------------------------------------------------------------
// K3: EMA buffer update
// ---------------------------------------------------------------------------
__global__ __launch_bounds__(256) void ema_kernel(const float* __restrict__ W,
                                                  const float* __restrict__ ema,
                                                  float* __restrict__ out) {
    const int t = blockIdx.x * 256 + threadIdx.x;   // 0..1048575
    out[t] = 0.25f * ema[t] + 0.75f * W[t];
}

// ---------------------------------------------------------------------------
// K4: perplexity + loss finalize (single block)
// ---------------------------------------------------------------------------
__global__ __launch_bounds__(256) void final_kernel(
        const int* __restrict__ counts, const double* __restrict__ loss_parts,
        float* __restrict__ out_loss, float* __restrict__ out_perp) {
    __shared__ float ps[256];
    __shared__ double ls[256];
    float s = 0.f;
    for (int c = threadIdx.x; c < N_E; c += 256) {
        const float p = (float)counts[c] * (1.0f / (float)NROWS);
        s += p * logf(p + 1e-10f);
    }
    double l = 0.0;
    for (int c = threadIdx.x; c < NLOSSPARTS; c += 256) l += loss_parts[c];
    ps[threadIdx.x] = s;
    ls[threadIdx.x] = l;
    __syncthreads();
    for (int off = 128; off > 0; off >>= 1) {
        if (threadIdx.x < off) {
            ps[threadIdx.x] += ps[threadIdx.x + off];
            ls[threadIdx.x] += ls[threadIdx.x + off];
        }
        __syncthreads();
    }
    if (threadIdx.x == 0) {
        *out_perp = expf(-ps[0]);
        const float m = (float)(ls[0] / (double)ZELEMS);
        *out_loss = m + 0.25f * m;
    }
}

// ---------------------------------------------------------------------------
extern "C" void kernel_launch(void* const* d_in, const int* in_sizes, int n_in,
                              void* d_out, int out_size, void* d_ws, size_t ws_size,
                              hipStream_t stream) {
    const float* z   = (const float*)d_in[0];
    const float* W   = (const float*)d_in[1];
    const float* ema = (const float*)d_in[2];
    float* out = (float*)d_out;

    float* out_loss   = out + OFF_LOSS;
    float* out_zq     = out + OFF_ZQ;
    float* out_perp   = out + OFF_PERP;
    float* out_onehot = out + OFF_ONEHOT;
    float* out_idx    = out + OFF_IDX;
    float* out_z      = out + OFF_ZOUT;
    float* out_ema    = out + OFF_EMA;

    // workspace layout
    char* ws = (char*)d_ws;
    int*    counts   = (int*)ws;                            // 16 KB
    int*    idxb     = (int*)(ws + 16384);                  // 64 KB
    float*  se       = (float*)(ws + 16384 + 65536);        // 16 KB
    float*  bDw      = (float*)(ws + 98304);                // 256 KB
    int*    bIw      = (int*)  (ws + 98304 + 262144);       // 256 KB
    double* lossp    = (double*)(ws + 98304 + 524288);      // 128 KB (all slots written)

    hipMemsetAsync(counts, 0, 16384, stream);   // counts only

    se_kernel<<<1024, 256, 0, stream>>>(W, se);
    argmin_kernel<<<dim3(NROWS / 128, NCHUNK), 512, 0, stream>>>(z, W, se, bDw, bIw);
    combine_kernel<<<NROWS * 64 / 256, 256, 0, stream>>>(bDw, bIw, idxb, counts,
                                                         out_idx, out_onehot);
    outputs_kernel<<<ZELEMS / 256, 256, 0, stream>>>(z, W, idxb, out_zq, out_z,
                                                     lossp);
    ema_kernel<<<(N_E * EDIM) / 256, 256, 0, stream>>>(W, ema, out_ema);
    final_kernel<<<1, 256, 0, stream>>>(counts, lossp, out_loss, out_perp);
}

// Round 8
// 778.975 us; speedup vs baseline: 2.2598x; 1.0356x over previous
//
#include <hip/hip_runtime.h>
#include <hip/hip_bf16.h>
#include <math.h>

// Problem constants
#define N_E    4096      // number of codes
#define EDIM   256       // embedding dim (K)
#define SPAT   8192      // 8*32*32 spatial per (b,c)
#define NROWS  16384     // NB * SPAT flattened rows
#define ZELEMS 4194304   // 2*256*8*32*32
#define NCHUNK 4         // code-dim split for occupancy
#define CHUNKC 1024      // codes per chunk
#define NLOSSPARTS 16384 // outputs_kernel grid size

// Output offsets (flat float32 in return order)
#define OFF_LOSS    0
#define OFF_ZQ      1
#define OFF_PERP    4194305
#define OFF_ONEHOT  4194306
#define OFF_IDX     71303170
#define OFF_ZOUT    71319554
#define OFF_EMA     75513858

// ---------------------------------------------------------------------------
// K0: se[c] = sum_k W[c][k]^2   (one wave per code)
// ---------------------------------------------------------------------------
__global__ __launch_bounds__(256) void se_kernel(const float* __restrict__ W,
                                                 float* __restrict__ se) {
    int wid  = (blockIdx.x * 256 + threadIdx.x) >> 6;   // wave id = code id
    int lane = threadIdx.x & 63;
    if (wid < N_E) {
        const float4 v = *(const float4*)(W + (size_t)wid * EDIM + lane * 4);
        float s = v.x * v.x + v.y * v.y + v.z * v.z + v.w * v.w;
        #pragma unroll
        for (int off = 32; off > 0; off >>= 1) s += __shfl_down(s, off);
        if (lane == 0) se[wid] = s;
    }
}

// ---------------------------------------------------------------------------
// K1: partial argmin — R6 version VERBATIM (known-good through replay
// validation; R7's register-prefetch pipeline produced replay-varying
// indices — unproven race, reverted).
// 128 rows x 1024 codes, fp32 vector GEMM, BM=128 BN=128 BK=32, 512 thr,
// 8x4 micro-tile. NO union (R2/R3: union-typed LDS scalarizes ds_read_b128).
// (512,4): VGPR cap 128 (benign per R3).
// ---------------------------------------------------------------------------
__global__ __launch_bounds__(512, 4) void argmin_kernel(
        const float* __restrict__ z, const float* __restrict__ W,
        const float* __restrict__ se,
        float* __restrict__ bDw, int* __restrict__ bIw) {
    __shared__ float As[32][128];   // 16 KB
    __shared__ float Bs[32][128];   // 16 KB
    __shared__ float szp[4][128];
    __shared__ float sz_s[128];
    __shared__ float rD[128];
    __shared__ int   rI[128];

    const int tid   = threadIdx.x;
    const int r0    = blockIdx.x * 128;       // first row of tile
    const int chunk = blockIdx.y;             // code chunk
    const int bb    = r0 >> 13;               // batch index
    const int sp0   = r0 & (SPAT - 1);        // spatial base (multiple of 128)
    const float* zb = z + (size_t)bb * (EDIM * SPAT) + sp0;

    // row norms: 512 threads, 4 k-chunks of 64 each over 128 rows
    {
        const int lr = tid & 127, kq = tid >> 7;
        float s = 0.f;
        const float* p = zb + lr + (size_t)(kq * 64) * SPAT;
        for (int k = 0; k < 64; ++k) {
            float v = p[(size_t)k * SPAT];
            s += v * v;
        }
        szp[kq][lr] = s;
    }
    __syncthreads();
    if (tid < 128)
        sz_s[tid] = ((szp[0][tid] + szp[1][tid]) + szp[2][tid]) + szp[3][tid];
    // (visibility of sz_s guaranteed by the first barrier inside the k0 loop)

    const int rg = tid >> 5;          // 0..15 -> rows rg*8..+7
    const int cg = tid & 31;          // 0..31 -> cols cg*4..+3 within tile
    const int a_kk = tid >> 4;              // 0..31
    const int a_lr = (tid & 15) << 3;       // 0,8,..,120
    const int b_lc = tid & 127;             // 0..127
    const int b_kq = tid >> 7;              // 0..3

    float bestD[8];
    int   bestI[8];
    #pragma unroll
    for (int i = 0; i < 8; ++i) { bestD[i] = 3.4e38f; bestI[i] = 0; }

    const int cbeg = chunk * CHUNKC;
    for (int c0 = cbeg; c0 < cbeg + CHUNKC; c0 += 128) {
        float acc[8][4];
        #pragma unroll
        for (int i = 0; i < 8; ++i)
            #pragma unroll
            for (int j = 0; j < 4; ++j) acc[i][j] = 0.f;

        for (int k0 = 0; k0 < EDIM; k0 += 32) {
            __syncthreads();   // previous iter's LDS reads done
            const float4 av0 = *(const float4*)(zb + (size_t)(k0 + a_kk) * SPAT + a_lr);
            const float4 av1 = *(const float4*)(zb + (size_t)(k0 + a_kk) * SPAT + a_lr + 4);
            *(float4*)&As[a_kk][a_lr]     = av0;
            *(float4*)&As[a_kk][a_lr + 4] = av1;
            #pragma unroll
            for (int t = 0; t < 2; ++t) {
                int kk = b_kq * 8 + t * 4;
                const float4 bv = *(const float4*)(W + (size_t)(c0 + b_lc) * EDIM + k0 + kk);
                Bs[kk + 0][b_lc] = bv.x;
                Bs[kk + 1][b_lc] = bv.y;
                Bs[kk + 2][b_lc] = bv.z;
                Bs[kk + 3][b_lc] = bv.w;
            }
            __syncthreads();
            #pragma unroll
            for (int kk = 0; kk < 32; ++kk) {
                const float4 a0 = *(const float4*)&As[kk][rg << 3];
                const float4 a1 = *(const float4*)&As[kk][(rg << 3) + 4];
                const float4 b  = *(const float4*)&Bs[kk][cg << 2];
                acc[0][0] += a0.x * b.x; acc[0][1] += a0.x * b.y;
                acc[0][2] += a0.x * b.z; acc[0][3] += a0.x * b.w;
                acc[1][0] += a0.y * b.x; acc[1][1] += a0.y * b.y;
                acc[1][2] += a0.y * b.z; acc[1][3] += a0.y * b.w;
                acc[2][0] += a0.z * b.x; acc[2][1] += a0.z * b.y;
                acc[2][2] += a0.z * b.z; acc[2][3] += a0.z * b.w;
                acc[3][0] += a0.w * b.x; acc[3][1] += a0.w * b.y;
                acc[3][2] += a0.w * b.z; acc[3][3] += a0.w * b.w;
                acc[4][0] += a1.x * b.x; acc[4][1] += a1.x * b.y;
                acc[4][2] += a1.x * b.z; acc[4][3] += a1.x * b.w;
                acc[5][0] += a1.y * b.x; acc[5][1] += a1.y * b.y;
                acc[5][2] += a1.y * b.z; acc[5][3] += a1.y * b.w;
                acc[6][0] += a1.z * b.x; acc[6][1] += a1.z * b.y;
                acc[6][2] += a1.z * b.z; acc[6][3] += a1.z * b.w;
                acc[7][0] += a1.w * b.x; acc[7][1] += a1.w * b.y;
                acc[7][2] += a1.w * b.z; acc[7][3] += a1.w * b.w;
            }
        }
        // distances + running argmin (codes ascend => first-min kept)
        #pragma unroll
        for (int i = 0; i < 8; ++i) {
            const float szr = sz_s[(rg << 3) + i];
            #pragma unroll
            for (int j = 0; j < 4; ++j) {
                const int code = c0 + (cg << 2) + j;
                const float d = (szr + se[code]) - 2.0f * acc[i][j];
                if (d < bestD[i]) { bestD[i] = d; bestI[i] = code; }
            }
        }
    }

    // shfl_xor butterfly across the 32-lane column group (masks <=16 stay
    // inside each half-wave; all lanes of a half share the same 8 rows)
    #pragma unroll
    for (int mask = 16; mask > 0; mask >>= 1) {
        #pragma unroll
        for (int i = 0; i < 8; ++i) {
            const float od = __shfl_xor(bestD[i], mask);
            const int   oi = __shfl_xor(bestI[i], mask);
            if (od < bestD[i] || (od == bestD[i] && oi < bestI[i])) {
                bestD[i] = od; bestI[i] = oi;
            }
        }
    }
    if (cg == 0) {
        #pragma unroll
        for (int i = 0; i < 8; ++i) {
            rD[(rg << 3) + i] = bestD[i];
            rI[(rg << 3) + i] = bestI[i];
        }
    }
    __syncthreads();
    if (tid < 128) {
        bDw[chunk * NROWS + r0 + tid] = rD[tid];
        bIw[chunk * NROWS + r0 + tid] = rI[tid];
    }
}

// ---------------------------------------------------------------------------
// K1b: combine partial argmins + write one-hot rows (zeros AND ones, fused).
// One wave per row. R8: global atomicAdd(counts) REMOVED — data-dependent
// code concentration serialized 16384 atomics on few L2 addresses (~200us+);
// histogram moved to final_kernel's LDS.
// ---------------------------------------------------------------------------
__global__ __launch_bounds__(256) void combine_kernel(
        const float* __restrict__ bDw, const int* __restrict__ bIw,
        int* __restrict__ idx_ws,
        float* __restrict__ out_idx, float* __restrict__ out_onehot) {
    const int g    = blockIdx.x * 256 + threadIdx.x;
    const int row  = g >> 6;          // wave-per-row
    const int lane = g & 63;

    float d0 = bDw[row];
    int   i0 = bIw[row];
    #pragma unroll
    for (int c = 1; c < NCHUNK; ++c) {
        const float d  = bDw[c * NROWS + row];
        const int   ii = bIw[c * NROWS + row];
        if (d < d0 || (d == d0 && ii < i0)) { d0 = d; i0 = ii; }
    }
    if (lane == 0) {
        idx_ws[row]  = i0;
        out_idx[row] = (float)i0;
    }
    float* dst = out_onehot + (size_t)row * N_E;
    #pragma unroll
    for (int w = 0; w < 16; ++w) {
        const int cb = w * 256 + lane * 4;
        float4 v;
        v.x = (cb + 0 == i0) ? 1.0f : 0.0f;
        v.y = (cb + 1 == i0) ? 1.0f : 0.0f;
        v.z = (cb + 2 == i0) ? 1.0f : 0.0f;
        v.w = (cb + 3 == i0) ? 1.0f : 0.0f;
        *(float4*)(dst + cb) = v;
    }
}

// ---------------------------------------------------------------------------
// K2: z_q_out, z_out, loss partials (per-block slots; R5: single-address
// f64 atomic from 16384 blocks serialized ~150us).
// ---------------------------------------------------------------------------
__global__ __launch_bounds__(256) void outputs_kernel(
        const float* __restrict__ z, const float* __restrict__ W,
        const int* __restrict__ idx,
        float* __restrict__ zq_out, float* __restrict__ z_out,
        double* __restrict__ loss_parts) {
    const int t  = blockIdx.x * 256 + threadIdx.x;     // 0..ZELEMS-1
    const float zv = z[t];
    const int sp = t & (SPAT - 1);
    const int c  = (t >> 13) & 255;
    const int b  = t >> 21;
    const int n  = (b << 13) + sp;
    const int id = idx[n];
    const float e    = W[id * EDIM + c];
    const float diff = e - zv;        // z_q - zp
    zq_out[t] = zv + diff;            // straight-through value, exact rounding
    z_out[t]  = zv;

    double ds = (double)(diff * diff);
    #pragma unroll
    for (int off = 32; off > 0; off >>= 1) ds += __shfl_down(ds, off);
    __shared__ double bsum[4];
    const int lane = threadIdx.x & 63, w = threadIdx.x >> 6;
    if (lane == 0) bsum[w] = ds;
    __syncthreads();
    if (threadIdx.x == 0)
        loss_parts[blockIdx.x] = bsum[0] + bsum[1] + bsum[2] + bsum[3];
}

// ---------------------------------------------------------------------------
// K3: EMA buffer update
// ---------------------------------------------------------------------------
__global__ __launch_bounds__(256) void ema_kernel(const float* __restrict__ W,
                                                  const float* __restrict__ ema,
                                                  float* __restrict__ out) {
    const int t = blockIdx.x * 256 + threadIdx.x;   // 0..1048575
    out[t] = 0.25f * ema[t] + 0.75f * W[t];
}

// ---------------------------------------------------------------------------
// K4: histogram (LDS) + perplexity + loss finalize (single 1024-thr block).
// LDS atomics keep hot-code contention on-CU (~4-8 cyc/op) instead of L2.
// ---------------------------------------------------------------------------
__global__ __launch_bounds__(1024) void final_kernel(
        const int* __restrict__ idx, const double* __restrict__ loss_parts,
        float* __restrict__ out_loss, float* __restrict__ out_perp) {
    __shared__ int   hist[N_E];    // 16 KB
    __shared__ float ps[1024];
    __shared__ double ls[1024];
    const int tid = threadIdx.x;

    for (int i = tid; i < N_E; i += 1024) hist[i] = 0;
    __syncthreads();
    for (int r = tid; r < NROWS; r += 1024) atomicAdd(&hist[idx[r]], 1);
    __syncthreads();

    float s = 0.f;
    for (int c = tid; c < N_E; c += 1024) {
        const float p = (float)hist[c] * (1.0f / (float)NROWS);
        s += p * logf(p + 1e-10f);
    }
    double l = 0.0;
    for (int c = tid; c < NLOSSPARTS; c += 1024) l += loss_parts[c];
    ps[tid] = s;
    ls[tid] = l;
    __syncthreads();
    for (int off = 512; off > 0; off >>= 1) {
        if (tid < off) {
            ps[tid] += ps[tid + off];
            ls[tid] += ls[tid + off];
        }
        __syncthreads();
    }
    if (tid == 0) {
        *out_perp = expf(-ps[0]);
        const float m = (float)(ls[0] / (double)ZELEMS);
        *out_loss = m + 0.25f * m;
    }
}

// ---------------------------------------------------------------------------
extern "C" void kernel_launch(void* const* d_in, const int* in_sizes, int n_in,
                              void* d_out, int out_size, void* d_ws, size_t ws_size,
                              hipStream_t stream) {
    const float* z   = (const float*)d_in[0];
    const float* W   = (const float*)d_in[1];
    const float* ema = (const float*)d_in[2];
    float* out = (float*)d_out;

    float* out_loss   = out + OFF_LOSS;
    float* out_zq     = out + OFF_ZQ;
    float* out_perp   = out + OFF_PERP;
    float* out_onehot = out + OFF_ONEHOT;
    float* out_idx    = out + OFF_IDX;
    float* out_z      = out + OFF_ZOUT;
    float* out_ema    = out + OFF_EMA;

    // workspace layout (every byte used is fully written each launch)
    char* ws = (char*)d_ws;
    int*    idxb     = (int*)ws;                            // 64 KB
    float*  se       = (float*)(ws + 65536);                // 16 KB
    float*  bDw      = (float*)(ws + 81920);                // 256 KB
    int*    bIw      = (int*)  (ws + 81920 + 262144);       // 256 KB
    double* lossp    = (double*)(ws + 81920 + 524288);      // 128 KB

    se_kernel<<<1024, 256, 0, stream>>>(W, se);
    argmin_kernel<<<dim3(NROWS / 128, NCHUNK), 512, 0, stream>>>(z, W, se, bDw, bIw);
    combine_kernel<<<NROWS * 64 / 256, 256, 0, stream>>>(bDw, bIw, idxb,
                                                         out_idx, out_onehot);
    outputs_kernel<<<ZELEMS / 256, 256, 0, stream>>>(z, W, idxb, out_zq, out_z,
                                                     lossp);
    ema_kernel<<<(N_E * EDIM) / 256, 256, 0, stream>>>(W, ema, out_ema);
    final_kernel<<<1, 1024, 0, stream>>>(idxb, lossp, out_loss, out_perp);
}